// Round 2
// baseline (784.232 us; speedup 1.0000x reference)
//
#include <hip/hip_runtime.h>
#include <hip/hip_bf16.h>
#include <stdint.h>

#define D 300
#define DP 320  // padded output-column dim (multiple of 64)

typedef __hip_bfloat16 bf16;

// ---------------- degree / dinv ----------------
__global__ void k_init(int* __restrict__ deg, int* __restrict__ cursor, int n) {
    int i = blockIdx.x * 256 + threadIdx.x;
    if (i < n) { deg[i] = 1; cursor[i] = 0; }  // self-loop counts 1
}

__global__ void k_count(const int* __restrict__ col, int* __restrict__ deg, int e) {
    int i = blockIdx.x * 256 + threadIdx.x;
    if (i < e) atomicAdd(&deg[col[i]], 1);
}

__global__ void k_dinv(const int* __restrict__ deg, float* __restrict__ dinv, int n) {
    int i = blockIdx.x * 256 + threadIdx.x;
    if (i < n) dinv[i] = rsqrtf((float)deg[i]);
}

// ---------------- exclusive scan of (deg[i]-1) = in-degree ----------------
__global__ void k_scanA(const int* __restrict__ deg, int* __restrict__ ex,
                        int* __restrict__ bsum, int n) {
    __shared__ int sh[256];
    int tid = threadIdx.x;
    int base = blockIdx.x * 1024 + tid * 4;
    int v[4]; int s = 0;
#pragma unroll
    for (int t = 0; t < 4; t++) {
        int i = base + t;
        v[t] = (i < n) ? (deg[i] - 1) : 0;
        s += v[t];
    }
    sh[tid] = s;
    __syncthreads();
    for (int off = 1; off < 256; off <<= 1) {
        int t = (tid >= off) ? sh[tid - off] : 0;
        __syncthreads();
        sh[tid] += t;
        __syncthreads();
    }
    int excl = sh[tid] - s;
#pragma unroll
    for (int t = 0; t < 4; t++) {
        int i = base + t;
        if (i < n) ex[i] = excl;
        excl += v[t];
    }
    if (tid == 255) bsum[blockIdx.x] = sh[255];
}

__global__ void k_scanB(const int* __restrict__ bsum, int* __restrict__ bexc, int nb) {
    __shared__ int sh[256];
    int tid = threadIdx.x;
    int s = (tid < nb) ? bsum[tid] : 0;
    sh[tid] = s;
    __syncthreads();
    for (int off = 1; off < 256; off <<= 1) {
        int t = (tid >= off) ? sh[tid - off] : 0;
        __syncthreads();
        sh[tid] += t;
        __syncthreads();
    }
    bexc[tid] = sh[tid] - s;
}

__global__ void k_scanC(int* __restrict__ starts, const int* __restrict__ bexc, int n) {
    int i = blockIdx.x * 256 + threadIdx.x;
    if (i < n) starts[i] += bexc[i >> 10];
}

// ---------------- CSR fill (by destination) ----------------
__global__ void k_fill(const int* __restrict__ ei, const float* __restrict__ dinv,
                       const int* __restrict__ starts, int* __restrict__ cursor,
                       int* __restrict__ srcidx, float* __restrict__ wedge, int e) {
    int i = blockIdx.x * 256 + threadIdx.x;
    if (i < e) {
        int r = ei[i];          // source
        int c = ei[e + i];      // destination (aggregation index)
        int p = atomicAdd(&cursor[c], 1);
        int slot = starts[c] + p;
        srcidx[slot] = r;
        wedge[slot] = dinv[r] * dinv[c];
    }
}

// ---------------- gather: one wave per node, h row in registers ----------------
__global__ void k_gather(const float* __restrict__ x, const int* __restrict__ srcidx,
                         const float* __restrict__ wedge, const int* __restrict__ starts,
                         const int* __restrict__ deg, const float* __restrict__ dinv,
                         bf16* __restrict__ hb, int n) {
    int w = (blockIdx.x * blockDim.x + threadIdx.x) >> 6;
    if (w >= n) return;
    int lane = threadIdx.x & 63;
    int s = starts[w];
    int cnt = deg[w] - 1;
    float dc = dinv[w];
    float a0 = 0.f, a1 = 0.f, a2 = 0.f, a3 = 0.f, a4 = 0.f;
    const bool d4ok = lane < (D - 256);  // lanes 0..43 hold d = lane+256
    for (int t = 0; t < cnt; t++) {
        int r = srcidx[s + t];
        float wg = wedge[s + t];
        const float* xr = x + (size_t)r * D + lane;
        a0 += wg * xr[0];
        a1 += wg * xr[64];
        a2 += wg * xr[128];
        a3 += wg * xr[192];
        if (d4ok) a4 += wg * xr[256];
    }
    const float* xc = x + (size_t)w * D + lane;
    float sw = dc * dc;  // self-loop weight
    bf16* hc = hb + (size_t)w * D + lane;
    hc[0]   = __float2bfloat16(a0 + sw * xc[0]);
    hc[64]  = __float2bfloat16(a1 + sw * xc[64]);
    hc[128] = __float2bfloat16(a2 + sw * xc[128]);
    hc[192] = __float2bfloat16(a3 + sw * xc[192]);
    if (d4ok) hc[256] = __float2bfloat16(a4 + sw * xc[256]);
}

// ---------------- W transpose with zero pad to DP cols ----------------
__global__ void k_tw(const float* __restrict__ W, float* __restrict__ WT2) {
    int idx = blockIdx.x * 256 + threadIdx.x;
    if (idx < D * DP) {
        int k = idx / DP, j = idx - k * DP;
        WT2[idx] = (j < D) ? W[j * D + k] : 0.f;
    }
}

// ---------------- fused GEMM + bias + relu + row L2-normalize + fp32 store ----
__global__ __launch_bounds__(DP)
void k_gemm(const bf16* __restrict__ hb, const float* __restrict__ WT2,
            const float* __restrict__ b, float* __restrict__ out, int n) {
    __shared__ float hsT[D * 32];  // [k][i], 38.4 KB
    __shared__ float red[32];
    int tid = threadIdx.x;
    int i0 = blockIdx.x * 32;
    // stage 32 h-rows, k-major, fp32
    for (int idx = tid; idx < 32 * D; idx += DP) {
        int i = idx / D, k = idx - i * D;
        int ri = i0 + i; if (ri >= n) ri = n - 1;
        hsT[k * 32 + i] = __bfloat162float(hb[(size_t)ri * D + k]);
    }
    if (tid < 32) red[tid] = 0.f;
    __syncthreads();

    float acc[32];
#pragma unroll
    for (int i = 0; i < 32; i++) acc[i] = 0.f;
    for (int k = 0; k < D; k++) {
        float wv = WT2[k * DP + tid];   // zero for tid >= 300
        const float4* hp = (const float4*)&hsT[k * 32];
#pragma unroll
        for (int g = 0; g < 8; g++) {
            float4 v = hp[g];
            acc[g * 4 + 0] += v.x * wv;
            acc[g * 4 + 1] += v.y * wv;
            acc[g * 4 + 2] += v.z * wv;
            acc[g * 4 + 3] += v.w * wv;
        }
    }

    float bj = (tid < D) ? b[tid] : 0.f;
    float vals[32];
#pragma unroll
    for (int i = 0; i < 32; i++) {
        float v = acc[i] + bj;          // pads: 0+0 -> relu 0, no norm pollution
        vals[i] = v > 0.f ? v : 0.f;
    }
    // per-row sum of squares: wave shuffle reduce, then one LDS atomic per wave
#pragma unroll
    for (int i = 0; i < 32; i++) {
        float sq = vals[i] * vals[i];
#pragma unroll
        for (int off = 32; off > 0; off >>= 1) sq += __shfl_xor(sq, off);
        if ((tid & 63) == 0) atomicAdd(&red[i], sq);
    }
    __syncthreads();
    if (tid < D) {
        float* op = out + (size_t)i0 * D + tid;
#pragma unroll
        for (int i = 0; i < 32; i++) {
            if (i0 + i < n) {
                float sc = 1.f / fmaxf(sqrtf(red[i]), 1e-12f);
                op[(size_t)i * D] = vals[i] * sc;
            }
        }
    }
}

// ---------------- host launch ----------------
extern "C" void kernel_launch(void* const* d_in, const int* in_sizes, int n_in,
                              void* d_out, int out_size, void* d_ws, size_t ws_size,
                              hipStream_t stream) {
    const float* x  = (const float*)d_in[0];
    const int*   ei = (const int*)d_in[1];
    const float* W  = (const float*)d_in[2];
    const float* b  = (const float*)d_in[3];
    float* out = (float*)d_out;
    int n = in_sizes[0] / D;
    int e = in_sizes[1] / 2;

    char* p = (char*)d_ws;
    bf16* hb = (bf16*)p;        p += (size_t)n * D * sizeof(bf16);
    p = (char*)(((uintptr_t)p + 15) & ~(uintptr_t)15);
    int* deg = (int*)p;         p += (size_t)n * 4;
    float* dinv = (float*)p;    p += (size_t)n * 4;
    int* starts = (int*)p;      p += (size_t)n * 4;
    int* cursor = (int*)p;      p += (size_t)n * 4;
    int* srcidx = (int*)p;      p += (size_t)e * 4;
    float* wedge = (float*)p;   p += (size_t)e * 4;
    int* bsum = (int*)p;        p += 256 * 4;
    int* bexc = (int*)p;        p += 256 * 4;
    float* WT2 = (float*)p;     p += (size_t)D * DP * 4;

    int nb = (n + 1023) / 1024;  // 98 <= 256, fits k_scanB

    k_init <<<(n + 255) / 256, 256, 0, stream>>>(deg, cursor, n);
    k_count<<<(e + 255) / 256, 256, 0, stream>>>(ei + e, deg, e);
    k_dinv <<<(n + 255) / 256, 256, 0, stream>>>(deg, dinv, n);
    k_scanA<<<nb, 256, 0, stream>>>(deg, starts, bsum, n);
    k_scanB<<<1, 256, 0, stream>>>(bsum, bexc, nb);
    k_scanC<<<(n + 255) / 256, 256, 0, stream>>>(starts, bexc, n);
    k_fill <<<(e + 255) / 256, 256, 0, stream>>>(ei, dinv, starts, cursor, srcidx, wedge, e);
    k_tw   <<<(D * DP + 255) / 256, 256, 0, stream>>>(W, WT2);
    k_gather<<<(n + 3) / 4, 256, 0, stream>>>(x, srcidx, wedge, starts, deg, dinv, hb, n);
    k_gemm <<<(n + 31) / 32, DP, 0, stream>>>(hb, WT2, b, out, n);
}

// Round 3
// 442.292 us; speedup vs baseline: 1.7731x; 1.7731x over previous
//
#include <hip/hip_runtime.h>
#include <hip/hip_bf16.h>
#include <stdint.h>

#define D 300
#define KP 320   // K padded to 10*32
#define JP 304   // out-col padded to 19*16
#define NT 19    // col tiles per row-tile

typedef __hip_bfloat16 bf16;
typedef __bf16 bf16x8 __attribute__((ext_vector_type(8)));
typedef unsigned short us8 __attribute__((ext_vector_type(8)));
typedef float f32x4 __attribute__((ext_vector_type(4)));

static __device__ __forceinline__ unsigned short f2bu(float f) {
    bf16 h = __float2bfloat16(f);
    return *reinterpret_cast<unsigned short*>(&h);
}
static __device__ __forceinline__ float bu2f(unsigned short u) {
    return __uint_as_float(((unsigned int)u) << 16);
}

// ---------------- degree / dinv ----------------
__global__ void k_init(int* __restrict__ deg, int* __restrict__ cursor, int n) {
    int i = blockIdx.x * 256 + threadIdx.x;
    if (i < n) { deg[i] = 1; cursor[i] = 0; }  // self-loop counts 1
}

__global__ void k_count(const int* __restrict__ col, int* __restrict__ deg, int e) {
    int i = blockIdx.x * 256 + threadIdx.x;
    if (i < e) atomicAdd(&deg[col[i]], 1);
}

__global__ void k_dinv(const int* __restrict__ deg, float* __restrict__ dinv, int n) {
    int i = blockIdx.x * 256 + threadIdx.x;
    if (i < n) dinv[i] = rsqrtf((float)deg[i]);
}

// ---------------- exclusive scan of (deg[i]-1) = in-degree ----------------
__global__ void k_scanA(const int* __restrict__ deg, int* __restrict__ ex,
                        int* __restrict__ bsum, int n) {
    __shared__ int sh[256];
    int tid = threadIdx.x;
    int base = blockIdx.x * 1024 + tid * 4;
    int v[4]; int s = 0;
#pragma unroll
    for (int t = 0; t < 4; t++) {
        int i = base + t;
        v[t] = (i < n) ? (deg[i] - 1) : 0;
        s += v[t];
    }
    sh[tid] = s;
    __syncthreads();
    for (int off = 1; off < 256; off <<= 1) {
        int t = (tid >= off) ? sh[tid - off] : 0;
        __syncthreads();
        sh[tid] += t;
        __syncthreads();
    }
    int excl = sh[tid] - s;
#pragma unroll
    for (int t = 0; t < 4; t++) {
        int i = base + t;
        if (i < n) ex[i] = excl;
        excl += v[t];
    }
    if (tid == 255) bsum[blockIdx.x] = sh[255];
}

__global__ void k_scanB(const int* __restrict__ bsum, int* __restrict__ bexc, int nb) {
    __shared__ int sh[256];
    int tid = threadIdx.x;
    int s = (tid < nb) ? bsum[tid] : 0;
    sh[tid] = s;
    __syncthreads();
    for (int off = 1; off < 256; off <<= 1) {
        int t = (tid >= off) ? sh[tid - off] : 0;
        __syncthreads();
        sh[tid] += t;
        __syncthreads();
    }
    bexc[tid] = sh[tid] - s;
}

__global__ void k_scanC(int* __restrict__ starts, const int* __restrict__ bexc, int n) {
    int i = blockIdx.x * 256 + threadIdx.x;
    if (i < n) starts[i] += bexc[i >> 10];
}

// ---------------- CSR fill (by destination) ----------------
__global__ void k_fill(const int* __restrict__ ei, const float* __restrict__ dinv,
                       const int* __restrict__ starts, int* __restrict__ cursor,
                       int* __restrict__ srcidx, float* __restrict__ wedge, int e) {
    int i = blockIdx.x * 256 + threadIdx.x;
    if (i < e) {
        int r = ei[i];          // source
        int c = ei[e + i];      // destination (aggregation index)
        int p = atomicAdd(&cursor[c], 1);
        int slot = starts[c] + p;
        srcidx[slot] = r;
        wedge[slot] = dinv[r] * dinv[c];
    }
}

// ---------------- x -> bf16 ----------------
__global__ void k_cvtx(const float* __restrict__ x, unsigned short* __restrict__ xb,
                       long total) {
    long i = ((long)blockIdx.x * 256 + threadIdx.x) * 4;
    if (i + 3 < total) {
        float4 v = *(const float4*)(x + i);
        ushort4 o;
        o.x = f2bu(v.x); o.y = f2bu(v.y); o.z = f2bu(v.z); o.w = f2bu(v.w);
        *(ushort4*)(xb + i) = o;
    }
}

// ---------------- W -> bf16 B^T layout [JP][KP], zero-padded ----------------
__global__ void k_twb(const float* __restrict__ W, unsigned short* __restrict__ wbp) {
    int idx = blockIdx.x * 256 + threadIdx.x;
    if (idx < JP * KP) {
        int j = idx / KP, k = idx - j * KP;
        wbp[idx] = (j < D && k < D) ? f2bu(W[j * D + k]) : (unsigned short)0;
    }
}

// ---------------- gather (fp32 x): one wave per node ----------------
__global__ void k_gather_f32(const float* __restrict__ x, const int* __restrict__ srcidx,
                             const float* __restrict__ wedge, const int* __restrict__ starts,
                             const int* __restrict__ deg, const float* __restrict__ dinv,
                             unsigned short* __restrict__ hbp, int n) {
    int w = (blockIdx.x * blockDim.x + threadIdx.x) >> 6;
    if (w >= n) return;
    int lane = threadIdx.x & 63;
    int s = starts[w];
    int cnt = deg[w] - 1;
    float dc = dinv[w];
    float a0 = 0.f, a1 = 0.f, a2 = 0.f, a3 = 0.f, a4 = 0.f;
    const bool d4 = lane < (D - 256);
    int t = 0;
    for (; t + 2 <= cnt; t += 2) {
        int r0 = srcidx[s + t], r1 = srcidx[s + t + 1];
        float w0 = wedge[s + t], w1 = wedge[s + t + 1];
        const float* p0 = x + (size_t)r0 * D + lane;
        const float* p1 = x + (size_t)r1 * D + lane;
        float v00 = p0[0], v01 = p0[64], v02 = p0[128], v03 = p0[192];
        float v10 = p1[0], v11 = p1[64], v12 = p1[128], v13 = p1[192];
        float v04 = d4 ? p0[256] : 0.f;
        float v14 = d4 ? p1[256] : 0.f;
        a0 += w0 * v00; a1 += w0 * v01; a2 += w0 * v02; a3 += w0 * v03; a4 += w0 * v04;
        a0 += w1 * v10; a1 += w1 * v11; a2 += w1 * v12; a3 += w1 * v13; a4 += w1 * v14;
    }
    if (t < cnt) {
        int r = srcidx[s + t];
        float wg = wedge[s + t];
        const float* xr = x + (size_t)r * D + lane;
        a0 += wg * xr[0]; a1 += wg * xr[64]; a2 += wg * xr[128]; a3 += wg * xr[192];
        if (d4) a4 += wg * xr[256];
    }
    const float* xc = x + (size_t)w * D + lane;
    float sw = dc * dc;
    a0 += sw * xc[0]; a1 += sw * xc[64]; a2 += sw * xc[128]; a3 += sw * xc[192];
    if (d4) a4 += sw * xc[256];
    unsigned short* hc = hbp + (size_t)w * KP + lane;
    hc[0]   = f2bu(a0);
    hc[64]  = f2bu(a1);
    hc[128] = f2bu(a2);
    hc[192] = f2bu(a3);
    hc[256] = d4 ? f2bu(a4) : (unsigned short)0;   // pads k=300..319 with 0
}

// ---------------- gather (bf16 x): one wave per node ----------------
__global__ void k_gather_bf(const unsigned short* __restrict__ xb, const int* __restrict__ srcidx,
                            const float* __restrict__ wedge, const int* __restrict__ starts,
                            const int* __restrict__ deg, const float* __restrict__ dinv,
                            unsigned short* __restrict__ hbp, int n) {
    int w = (blockIdx.x * blockDim.x + threadIdx.x) >> 6;
    if (w >= n) return;
    int lane = threadIdx.x & 63;
    int s = starts[w];
    int cnt = deg[w] - 1;
    float dc = dinv[w];
    float a0 = 0.f, a1 = 0.f, a2 = 0.f, a3 = 0.f, a4 = 0.f;
    const bool d4 = lane < (D - 256);
    int t = 0;
    for (; t + 2 <= cnt; t += 2) {
        int r0 = srcidx[s + t], r1 = srcidx[s + t + 1];
        float w0 = wedge[s + t], w1 = wedge[s + t + 1];
        const unsigned short* p0 = xb + (size_t)r0 * D + lane;
        const unsigned short* p1 = xb + (size_t)r1 * D + lane;
        float v00 = bu2f(p0[0]), v01 = bu2f(p0[64]), v02 = bu2f(p0[128]), v03 = bu2f(p0[192]);
        float v10 = bu2f(p1[0]), v11 = bu2f(p1[64]), v12 = bu2f(p1[128]), v13 = bu2f(p1[192]);
        float v04 = d4 ? bu2f(p0[256]) : 0.f;
        float v14 = d4 ? bu2f(p1[256]) : 0.f;
        a0 += w0 * v00; a1 += w0 * v01; a2 += w0 * v02; a3 += w0 * v03; a4 += w0 * v04;
        a0 += w1 * v10; a1 += w1 * v11; a2 += w1 * v12; a3 += w1 * v13; a4 += w1 * v14;
    }
    if (t < cnt) {
        int r = srcidx[s + t];
        float wg = wedge[s + t];
        const unsigned short* xr = xb + (size_t)r * D + lane;
        a0 += wg * bu2f(xr[0]); a1 += wg * bu2f(xr[64]); a2 += wg * bu2f(xr[128]);
        a3 += wg * bu2f(xr[192]);
        if (d4) a4 += wg * bu2f(xr[256]);
    }
    const unsigned short* xc = xb + (size_t)w * D + lane;
    float sw = dc * dc;
    a0 += sw * bu2f(xc[0]); a1 += sw * bu2f(xc[64]); a2 += sw * bu2f(xc[128]);
    a3 += sw * bu2f(xc[192]);
    if (d4) a4 += sw * bu2f(xc[256]);
    unsigned short* hc = hbp + (size_t)w * KP + lane;
    hc[0]   = f2bu(a0);
    hc[64]  = f2bu(a1);
    hc[128] = f2bu(a2);
    hc[192] = f2bu(a3);
    hc[256] = d4 ? f2bu(a4) : (unsigned short)0;
}

// ------ MFMA GEMM + bias + relu + row L2 norm + fp32 store, no LDS ------
// wave = 16 rows x 304 cols; block = 4 waves = 64 rows.
__global__ __launch_bounds__(256)
void k_mm(const unsigned short* __restrict__ hbp, const unsigned short* __restrict__ wbp,
          const float* __restrict__ bias, float* __restrict__ out, int n) {
    int lane = threadIdx.x & 63;
    int wid = threadIdx.x >> 6;
    int r0 = blockIdx.x * 64 + wid * 16;
    int lrow = lane & 15;   // A-row / B-col / D-col selector
    int kg = lane >> 4;     // k-group 0..3

    int arow = r0 + lrow; if (arow >= n) arow = n - 1;
    const us8* ap = (const us8*)(hbp + (size_t)arow * KP + kg * 8);
    const unsigned short* bb = wbp + (size_t)lrow * KP + kg * 8;

    f32x4 acc[NT];
#pragma unroll
    for (int t = 0; t < NT; t++) acc[t] = f32x4{0.f, 0.f, 0.f, 0.f};

    for (int kk = 0; kk < KP / 32; kk++) {
        bf16x8 a = __builtin_bit_cast(bf16x8, ap[kk * 4]);
        const unsigned short* bk = bb + kk * 32;
#pragma unroll
        for (int t = 0; t < NT; t++) {
            bf16x8 bv = __builtin_bit_cast(bf16x8, *(const us8*)(bk + (size_t)t * 16 * KP));
            acc[t] = __builtin_amdgcn_mfma_f32_16x16x32_bf16(a, bv, acc[t], 0, 0, 0);
        }
    }

    float bj[NT];
#pragma unroll
    for (int t = 0; t < NT; t++) {
        int j = t * 16 + lrow;
        bj[t] = (j < D) ? bias[j] : 0.f;
    }
    float sums[4] = {0.f, 0.f, 0.f, 0.f};
#pragma unroll
    for (int t = 0; t < NT; t++) {
#pragma unroll
        for (int r = 0; r < 4; r++) {
            float v = acc[t][r] + bj[t];
            v = v > 0.f ? v : 0.f;      // relu; pad cols give 0
            acc[t][r] = v;
            sums[r] += v * v;
        }
    }
#pragma unroll
    for (int r = 0; r < 4; r++) {
        float s = sums[r];
        s += __shfl_xor(s, 1);
        s += __shfl_xor(s, 2);
        s += __shfl_xor(s, 4);
        s += __shfl_xor(s, 8);          // reduce across the 16 lanes of this k-group
        sums[r] = rsqrtf(fmaxf(s, 1e-24f));  // == 1/max(sqrt(s),1e-12)
    }
#pragma unroll
    for (int r = 0; r < 4; r++) {
        int grow = r0 + kg * 4 + r;     // C/D: row=(lane>>4)*4+reg [m89]
        if (grow < n) {
            float* op = out + (size_t)grow * D;
#pragma unroll
            for (int t = 0; t < NT; t++) {
                int j = t * 16 + lrow;
                if (j < D) op[j] = acc[t][r] * sums[r];
            }
        }
    }
}

// ---------------- host launch ----------------
extern "C" void kernel_launch(void* const* d_in, const int* in_sizes, int n_in,
                              void* d_out, int out_size, void* d_ws, size_t ws_size,
                              hipStream_t stream) {
    const float* x  = (const float*)d_in[0];
    const int*   ei = (const int*)d_in[1];
    const float* W  = (const float*)d_in[2];
    const float* b  = (const float*)d_in[3];
    float* out = (float*)d_out;
    int n = in_sizes[0] / D;
    int e = in_sizes[1] / 2;

    char* p = (char*)d_ws;
    unsigned short* hbp = (unsigned short*)p; p += (size_t)n * KP * 2;
    int* deg = (int*)p;         p += (size_t)n * 4;
    float* dinv = (float*)p;    p += (size_t)n * 4;
    int* starts = (int*)p;      p += (size_t)n * 4;
    int* cursor = (int*)p;      p += (size_t)n * 4;
    int* srcidx = (int*)p;      p += (size_t)e * 4;
    float* wedge = (float*)p;   p += (size_t)e * 4;
    int* bsum = (int*)p;        p += 256 * 4;
    int* bexc = (int*)p;        p += 256 * 4;
    p = (char*)(((uintptr_t)p + 15) & ~(uintptr_t)15);
    unsigned short* wbp = (unsigned short*)p; p += (size_t)JP * KP * 2;
    p = (char*)(((uintptr_t)p + 15) & ~(uintptr_t)15);
    unsigned short* xb = (unsigned short*)p;
    size_t need_bf = (size_t)(p - (char*)d_ws) + (size_t)n * D * 2;
    bool usebf = (ws_size >= need_bf);

    int nb = (n + 1023) / 1024;

    k_init <<<(n + 255) / 256, 256, 0, stream>>>(deg, cursor, n);
    k_count<<<(e + 255) / 256, 256, 0, stream>>>(ei + e, deg, e);
    k_dinv <<<(n + 255) / 256, 256, 0, stream>>>(deg, dinv, n);
    k_scanA<<<nb, 256, 0, stream>>>(deg, starts, bsum, n);
    k_scanB<<<1, 256, 0, stream>>>(bsum, bexc, nb);
    k_scanC<<<(n + 255) / 256, 256, 0, stream>>>(starts, bexc, n);
    k_fill <<<(e + 255) / 256, 256, 0, stream>>>(ei, dinv, starts, cursor, srcidx, wedge, e);
    k_twb  <<<(JP * KP + 255) / 256, 256, 0, stream>>>(W, wbp);
    if (usebf) {
        long total = (long)n * D;
        k_cvtx<<<(int)((total / 4 + 255) / 256), 256, 0, stream>>>(x, xb, total);
        k_gather_bf<<<(n + 3) / 4, 256, 0, stream>>>(xb, srcidx, wedge, starts, deg, dinv, hbp, n);
    } else {
        k_gather_f32<<<(n + 3) / 4, 256, 0, stream>>>(x, srcidx, wedge, starts, deg, dinv, hbp, n);
    }
    k_mm <<<(n + 63) / 64, 256, 0, stream>>>(hbp, wbp, b, out, n);
}

// Round 4
// 305.697 us; speedup vs baseline: 2.5654x; 1.4468x over previous
//
#include <hip/hip_runtime.h>
#include <hip/hip_bf16.h>
#include <stdint.h>

#define D 300
#define KP 320   // K padded to 10*32
#define JP 304   // out-col padded to 19*16
#define NT 19    // col tiles (16 wide) per wave

typedef __hip_bfloat16 bf16;
typedef __bf16 bf16x8 __attribute__((ext_vector_type(8)));
typedef unsigned short us8 __attribute__((ext_vector_type(8)));
typedef float f32x4 __attribute__((ext_vector_type(4)));

static __device__ __forceinline__ unsigned short f2bu(float f) {
    bf16 h = __float2bfloat16(f);
    return *reinterpret_cast<unsigned short*>(&h);
}
static __device__ __forceinline__ float bu2f(unsigned short u) {
    return __uint_as_float(((unsigned int)u) << 16);
}
static __device__ __forceinline__ unsigned int packbf(float lo, float hi) {
    return (unsigned int)f2bu(lo) | ((unsigned int)f2bu(hi) << 16);
}
static __device__ __forceinline__ void gload_lds16(const void* g, void* l) {
    __builtin_amdgcn_global_load_lds(
        (const __attribute__((address_space(1))) unsigned int*)g,
        (__attribute__((address_space(3))) unsigned int*)l, 16, 0, 0);
}

// ---------------- degree / dinv ----------------
__global__ void k_init(int* __restrict__ deg, int* __restrict__ cursor, int n) {
    int i = blockIdx.x * 256 + threadIdx.x;
    if (i < n) { deg[i] = 1; cursor[i] = 0; }  // self-loop counts 1
}

__global__ void k_count(const int* __restrict__ col, int* __restrict__ deg, int e) {
    int i = blockIdx.x * 256 + threadIdx.x;
    if (i < e) atomicAdd(&deg[col[i]], 1);
}

__global__ void k_dinv(const int* __restrict__ deg, float* __restrict__ dinv, int n) {
    int i = blockIdx.x * 256 + threadIdx.x;
    if (i < n) dinv[i] = rsqrtf((float)deg[i]);
}

// ---------------- exclusive scan of (deg[i]-1) = in-degree ----------------
__global__ void k_scanA(const int* __restrict__ deg, int* __restrict__ ex,
                        int* __restrict__ bsum, int n) {
    __shared__ int sh[256];
    int tid = threadIdx.x;
    int base = blockIdx.x * 1024 + tid * 4;
    int v[4]; int s = 0;
#pragma unroll
    for (int t = 0; t < 4; t++) {
        int i = base + t;
        v[t] = (i < n) ? (deg[i] - 1) : 0;
        s += v[t];
    }
    sh[tid] = s;
    __syncthreads();
    for (int off = 1; off < 256; off <<= 1) {
        int t = (tid >= off) ? sh[tid - off] : 0;
        __syncthreads();
        sh[tid] += t;
        __syncthreads();
    }
    int excl = sh[tid] - s;
#pragma unroll
    for (int t = 0; t < 4; t++) {
        int i = base + t;
        if (i < n) ex[i] = excl;
        excl += v[t];
    }
    if (tid == 255) bsum[blockIdx.x] = sh[255];
}

__global__ void k_scanB(const int* __restrict__ bsum, int* __restrict__ bexc, int nb) {
    __shared__ int sh[256];
    int tid = threadIdx.x;
    int s = (tid < nb) ? bsum[tid] : 0;
    sh[tid] = s;
    __syncthreads();
    for (int off = 1; off < 256; off <<= 1) {
        int t = (tid >= off) ? sh[tid - off] : 0;
        __syncthreads();
        sh[tid] += t;
        __syncthreads();
    }
    bexc[tid] = sh[tid] - s;
}

__global__ void k_scanC(int* __restrict__ starts, const int* __restrict__ bexc, int n) {
    int i = blockIdx.x * 256 + threadIdx.x;
    if (i < n) starts[i] += bexc[i >> 10];
}

// ---------------- CSR fill (by destination) ----------------
__global__ void k_fill(const int* __restrict__ ei, const float* __restrict__ dinv,
                       const int* __restrict__ starts, int* __restrict__ cursor,
                       int* __restrict__ srcidx, float* __restrict__ wedge, int e) {
    int i = blockIdx.x * 256 + threadIdx.x;
    if (i < e) {
        int r = ei[i];          // source
        int c = ei[e + i];      // destination (aggregation index)
        int p = atomicAdd(&cursor[c], 1);
        int slot = starts[c] + p;
        srcidx[slot] = r;
        wedge[slot] = dinv[r] * dinv[c];
    }
}

// ---------------- x -> bf16 (packed uints, 16B stores) ----------------
__global__ void k_cvtx(const float* __restrict__ x, unsigned int* __restrict__ xb32,
                       long total8) {  // total8 = n*D/8 groups of 8 floats
    long g = (long)blockIdx.x * 256 + threadIdx.x;
    if (g < total8) {
        const float4* xp = (const float4*)(x + g * 8);
        float4 v0 = xp[0], v1 = xp[1];
        uint4 o;
        o.x = packbf(v0.x, v0.y); o.y = packbf(v0.z, v0.w);
        o.z = packbf(v1.x, v1.y); o.w = packbf(v1.z, v1.w);
        *(uint4*)(xb32 + g * 4) = o;
    }
}

// ---------------- W -> bf16 B^T layout [JP][KP], zero-padded ----------------
__global__ void k_twb(const float* __restrict__ W, unsigned short* __restrict__ wbp) {
    int idx = blockIdx.x * 256 + threadIdx.x;
    if (idx < JP * KP) {
        int j = idx / KP, k = idx - j * KP;
        wbp[idx] = (j < D && k < D) ? f2bu(W[j * D + k]) : (unsigned short)0;
    }
}

// ---------------- gather (fp32 x fallback): one wave per node ----------------
__global__ void k_gather_f32(const float* __restrict__ x, const int* __restrict__ srcidx,
                             const float* __restrict__ wedge, const int* __restrict__ starts,
                             const int* __restrict__ deg, const float* __restrict__ dinv,
                             unsigned short* __restrict__ hbp, int n) {
    int w = (blockIdx.x * blockDim.x + threadIdx.x) >> 6;
    if (w >= n) return;
    int lane = threadIdx.x & 63;
    int s = starts[w];
    int cnt = deg[w] - 1;
    float dc = dinv[w];
    float a0 = 0.f, a1 = 0.f, a2 = 0.f, a3 = 0.f, a4 = 0.f;
    const bool d4 = lane < (D - 256);
    for (int t = 0; t < cnt; t++) {
        int r = srcidx[s + t];
        float wg = wedge[s + t];
        const float* xr = x + (size_t)r * D + lane;
        a0 += wg * xr[0]; a1 += wg * xr[64]; a2 += wg * xr[128]; a3 += wg * xr[192];
        if (d4) a4 += wg * xr[256];
    }
    const float* xc = x + (size_t)w * D + lane;
    float sw = dc * dc;
    a0 += sw * xc[0]; a1 += sw * xc[64]; a2 += sw * xc[128]; a3 += sw * xc[192];
    if (d4) a4 += sw * xc[256];
    unsigned short* hc = hbp + (size_t)w * KP + lane;
    hc[0]   = f2bu(a0);
    hc[64]  = f2bu(a1);
    hc[128] = f2bu(a2);
    hc[192] = f2bu(a3);
    hc[256] = d4 ? f2bu(a4) : (unsigned short)0;
}

// ---------------- gather (bf16 x, uint loads): one wave per node ----------------
// row = 150 uints (300 bf16). lane covers pair-units {lane, 64+lane, 128+lane if lane<22}.
__global__ void k_gather_bf(const unsigned int* __restrict__ xb32, const int* __restrict__ srcidx,
                            const float* __restrict__ wedge, const int* __restrict__ starts,
                            const int* __restrict__ deg, const float* __restrict__ dinv,
                            unsigned int* __restrict__ hb32, int n) {
    int w = (blockIdx.x * blockDim.x + threadIdx.x) >> 6;
    if (w >= n) return;
    int lane = threadIdx.x & 63;
    int s = starts[w];
    int cnt = deg[w] - 1;
    float dc = dinv[w];
    const bool p2 = lane < 22;
    float a0l = 0.f, a0h = 0.f, a1l = 0.f, a1h = 0.f, a2l = 0.f, a2h = 0.f;
    int t = 0;
    for (; t + 2 <= cnt; t += 2) {
        int r0 = srcidx[s + t], r1 = srcidx[s + t + 1];
        float w0 = wedge[s + t], w1 = wedge[s + t + 1];
        const unsigned int* q0 = xb32 + (size_t)r0 * 150 + lane;
        const unsigned int* q1 = xb32 + (size_t)r1 * 150 + lane;
        unsigned int u00 = q0[0], u01 = q0[64];
        unsigned int u10 = q1[0], u11 = q1[64];
        unsigned int u02 = p2 ? q0[128] : 0u;
        unsigned int u12 = p2 ? q1[128] : 0u;
        a0l += w0 * bu2f(u00 & 0xffff); a0h += w0 * bu2f(u00 >> 16);
        a1l += w0 * bu2f(u01 & 0xffff); a1h += w0 * bu2f(u01 >> 16);
        a2l += w0 * bu2f(u02 & 0xffff); a2h += w0 * bu2f(u02 >> 16);
        a0l += w1 * bu2f(u10 & 0xffff); a0h += w1 * bu2f(u10 >> 16);
        a1l += w1 * bu2f(u11 & 0xffff); a1h += w1 * bu2f(u11 >> 16);
        a2l += w1 * bu2f(u12 & 0xffff); a2h += w1 * bu2f(u12 >> 16);
    }
    if (t < cnt) {
        int r = srcidx[s + t];
        float wg = wedge[s + t];
        const unsigned int* q = xb32 + (size_t)r * 150 + lane;
        unsigned int u0 = q[0], u1 = q[64];
        unsigned int u2 = p2 ? q[128] : 0u;
        a0l += wg * bu2f(u0 & 0xffff); a0h += wg * bu2f(u0 >> 16);
        a1l += wg * bu2f(u1 & 0xffff); a1h += wg * bu2f(u1 >> 16);
        a2l += wg * bu2f(u2 & 0xffff); a2h += wg * bu2f(u2 >> 16);
    }
    {
        const unsigned int* q = xb32 + (size_t)w * 150 + lane;
        float sw = dc * dc;
        unsigned int u0 = q[0], u1 = q[64];
        unsigned int u2 = p2 ? q[128] : 0u;
        a0l += sw * bu2f(u0 & 0xffff); a0h += sw * bu2f(u0 >> 16);
        a1l += sw * bu2f(u1 & 0xffff); a1h += sw * bu2f(u1 >> 16);
        a2l += sw * bu2f(u2 & 0xffff); a2h += sw * bu2f(u2 >> 16);
    }
    unsigned int* hr = hb32 + (size_t)w * (KP / 2);   // 160 uints per row
    hr[lane]      = packbf(a0l, a0h);
    hr[64 + lane] = packbf(a1l, a1h);
    if (p2)             hr[128 + lane] = packbf(a2l, a2h);
    else if (lane < 32) hr[128 + lane] = 0u;          // zero pads k=300..319
}

// ------ MFMA GEMM: LDS-staged B (kg-major), 2 row-tiles/wave, fused epilogue ------
// block = 4 waves = 128 rows; wave = 32 rows x 304 cols.
__global__ __launch_bounds__(256)
void k_mm(const unsigned short* __restrict__ hbp, const unsigned short* __restrict__ wbp,
          const float* __restrict__ bias, float* __restrict__ out, int n) {
    // LDS chunk layout (per buffer): unit u (16B) = kg*304 + j  ->  B[j][kk*32 + kg*8 ..+8]
    __shared__ unsigned short Bsh[2][JP * 32];   // 2 x 19456 B
    int tid = threadIdx.x;
    int lane = tid & 63, wid = tid >> 6;
    int r0 = blockIdx.x * 128 + wid * 32;
    int lrow = lane & 15, kg = lane >> 4;

    // ---- staging slot assignment: slots i = wid + 4j (i < 19), 1024 B each ----
    int goff[5];
#pragma unroll
    for (int j = 0; j < 5; j++) {
        int i = wid + 4 * j;
        if (i < 19) {
            int u = i * 64 + lane;
            int kgs = u / 304;
            int rs  = u - kgs * 304;
            goff[j] = rs * (KP * 2) + kgs * 16;   // byte offset in wbp (+ kk*64 later)
        }
    }
    const char* wb = (const char*)wbp;

    // ---- A pointers (2 row-tiles) ----
    int ar0 = r0 + lrow;      if (ar0 >= n) ar0 = n - 1;
    int ar1 = r0 + 16 + lrow; if (ar1 >= n) ar1 = n - 1;
    const us8* ap0 = (const us8*)(hbp + (size_t)ar0 * KP);
    const us8* ap1 = (const us8*)(hbp + (size_t)ar1 * KP);

    f32x4 acc0[NT], acc1[NT];
#pragma unroll
    for (int t = 0; t < NT; t++) {
        acc0[t] = f32x4{0.f, 0.f, 0.f, 0.f};
        acc1[t] = f32x4{0.f, 0.f, 0.f, 0.f};
    }

    // prologue: stage chunk 0, prefetch A frags for kk=0
    {
        char* lb = (char*)&Bsh[0][0];
#pragma unroll
        for (int j = 0; j < 5; j++) {
            int i = wid + 4 * j;
            if (i < 19) gload_lds16(wb + goff[j], lb + i * 1024);
        }
    }
    us8 a0 = ap0[kg], a1 = ap1[kg];
    __syncthreads();

    for (int kk = 0; kk < KP / 32; kk++) {
        // stage next chunk
        if (kk < KP / 32 - 1) {
            char* lb = (char*)&Bsh[(kk + 1) & 1][0];
            int gofs = (kk + 1) * 64;
#pragma unroll
            for (int j = 0; j < 5; j++) {
                int i = wid + 4 * j;
                if (i < 19) gload_lds16(wb + goff[j] + gofs, lb + i * 1024);
            }
        }
        // prefetch next A frags
        us8 a0n = a0, a1n = a1;
        if (kk < KP / 32 - 1) {
            a0n = ap0[(kk + 1) * 4 + kg];
            a1n = ap1[(kk + 1) * 4 + kg];
        }
        // compute on current chunk
        const unsigned short* bbase = &Bsh[kk & 1][0] + (kg * 304 + lrow) * 8;
        bf16x8 av0 = __builtin_bit_cast(bf16x8, a0);
        bf16x8 av1 = __builtin_bit_cast(bf16x8, a1);
#pragma unroll
        for (int t = 0; t < NT; t++) {
            bf16x8 bv = __builtin_bit_cast(bf16x8, *(const us8*)(bbase + t * 128));
            acc0[t] = __builtin_amdgcn_mfma_f32_16x16x32_bf16(av0, bv, acc0[t], 0, 0, 0);
            acc1[t] = __builtin_amdgcn_mfma_f32_16x16x32_bf16(av1, bv, acc1[t], 0, 0, 0);
        }
        a0 = a0n; a1 = a1n;
        __syncthreads();
    }

    // ---- epilogue: bias + relu + row L2 norm + store (both tiles) ----
    float bj[NT];
#pragma unroll
    for (int t = 0; t < NT; t++) {
        int j = t * 16 + lrow;
        bj[t] = (j < D) ? bias[j] : 0.f;
    }
    float s0[4] = {0.f, 0.f, 0.f, 0.f}, s1[4] = {0.f, 0.f, 0.f, 0.f};
#pragma unroll
    for (int t = 0; t < NT; t++) {
#pragma unroll
        for (int r = 0; r < 4; r++) {
            float v = acc0[t][r] + bj[t];
            v = v > 0.f ? v : 0.f;
            acc0[t][r] = v; s0[r] += v * v;
            float u = acc1[t][r] + bj[t];
            u = u > 0.f ? u : 0.f;
            acc1[t][r] = u; s1[r] += u * u;
        }
    }
#pragma unroll
    for (int r = 0; r < 4; r++) {
        float a = s0[r], b = s1[r];
        a += __shfl_xor(a, 1); b += __shfl_xor(b, 1);
        a += __shfl_xor(a, 2); b += __shfl_xor(b, 2);
        a += __shfl_xor(a, 4); b += __shfl_xor(b, 4);
        a += __shfl_xor(a, 8); b += __shfl_xor(b, 8);
        s0[r] = rsqrtf(fmaxf(a, 1e-24f));   // == 1/max(sqrt(a),1e-12)
        s1[r] = rsqrtf(fmaxf(b, 1e-24f));
    }
#pragma unroll
    for (int r = 0; r < 4; r++) {
        int g0 = r0 + kg * 4 + r;          // C/D: row=(lane>>4)*4+reg
        int g1 = r0 + 16 + kg * 4 + r;
        float* op0 = out + (size_t)g0 * D;
        float* op1 = out + (size_t)g1 * D;
#pragma unroll
        for (int t = 0; t < NT; t++) {
            int j = t * 16 + lrow;
            if (j < D) {
                if (g0 < n) op0[j] = acc0[t][r] * s0[r];
                if (g1 < n) op1[j] = acc1[t][r] * s1[r];
            }
        }
    }
}

// ---------------- host launch ----------------
extern "C" void kernel_launch(void* const* d_in, const int* in_sizes, int n_in,
                              void* d_out, int out_size, void* d_ws, size_t ws_size,
                              hipStream_t stream) {
    const float* x  = (const float*)d_in[0];
    const int*   ei = (const int*)d_in[1];
    const float* W  = (const float*)d_in[2];
    const float* b  = (const float*)d_in[3];
    float* out = (float*)d_out;
    int n = in_sizes[0] / D;
    int e = in_sizes[1] / 2;

    char* p = (char*)d_ws;
    unsigned short* hbp = (unsigned short*)p; p += (size_t)n * KP * 2;
    int* deg = (int*)p;         p += (size_t)n * 4;
    float* dinv = (float*)p;    p += (size_t)n * 4;
    int* starts = (int*)p;      p += (size_t)n * 4;
    int* cursor = (int*)p;      p += (size_t)n * 4;
    int* srcidx = (int*)p;      p += (size_t)e * 4;
    float* wedge = (float*)p;   p += (size_t)e * 4;
    int* bsum = (int*)p;        p += 256 * 4;
    int* bexc = (int*)p;        p += 256 * 4;
    p = (char*)(((uintptr_t)p + 15) & ~(uintptr_t)15);
    unsigned short* wbp = (unsigned short*)p; p += (size_t)JP * KP * 2;
    p = (char*)(((uintptr_t)p + 15) & ~(uintptr_t)15);
    unsigned int* xb32 = (unsigned int*)p;
    size_t need_bf = (size_t)(p - (char*)d_ws) + (size_t)n * D * 2;
    bool usebf = (ws_size >= need_bf);

    int nb = (n + 1023) / 1024;

    k_init <<<(n + 255) / 256, 256, 0, stream>>>(deg, cursor, n);
    k_count<<<(e + 255) / 256, 256, 0, stream>>>(ei + e, deg, e);
    k_dinv <<<(n + 255) / 256, 256, 0, stream>>>(deg, dinv, n);
    k_scanA<<<nb, 256, 0, stream>>>(deg, starts, bsum, n);
    k_scanB<<<1, 256, 0, stream>>>(bsum, bexc, nb);
    k_scanC<<<(n + 255) / 256, 256, 0, stream>>>(starts, bexc, n);
    k_fill <<<(e + 255) / 256, 256, 0, stream>>>(ei, dinv, starts, cursor, srcidx, wedge, e);
    k_twb  <<<(JP * KP + 255) / 256, 256, 0, stream>>>(W, wbp);
    if (usebf) {
        long total8 = (long)n * D / 8;   // n*D divisible by 8? n*300: use /4 groups guard
        // n*D = 30,000,000 -> divisible by 8? 30e6/8 = 3.75e6 exactly. handle generally:
        long g8 = ((long)n * D) / 8;
        k_cvtx<<<(int)((g8 + 255) / 256), 256, 0, stream>>>(x, xb32, g8);
        // tail (n*D % 8 floats) — for n*D multiple of 4 but not 8, convert last group scalar-free:
        // (N*D = 30M is a multiple of 8 for the bench; general tail handled by fp32 path otherwise)
        if (((long)n * D) % 8 != 0) {
            k_gather_f32<<<(n + 3) / 4, 256, 0, stream>>>(x, srcidx, wedge, starts, deg, dinv, hbp, n);
        } else {
            k_gather_bf<<<(n + 3) / 4, 256, 0, stream>>>(xb32, srcidx, wedge, starts, deg, dinv,
                                                         (unsigned int*)hbp, n);
        }
        (void)total8;
    } else {
        k_gather_f32<<<(n + 3) / 4, 256, 0, stream>>>(x, srcidx, wedge, starts, deg, dinv, hbp, n);
    }
    k_mm <<<(n + 127) / 128, 256, 0, stream>>>(hbp, wbp, b, out, n);
}

// Round 5
// 298.780 us; speedup vs baseline: 2.6248x; 1.0231x over previous
//
#include <hip/hip_runtime.h>
#include <hip/hip_bf16.h>
#include <stdint.h>

#define D 300
#define KP 320   // K padded to 10*32
#define JP 304   // out-col padded to 19*16
#define NT 19    // col tiles (16 wide) per wave

typedef __hip_bfloat16 bf16;
typedef __bf16 bf16x8 __attribute__((ext_vector_type(8)));
typedef unsigned short us8 __attribute__((ext_vector_type(8)));
typedef float f32x4 __attribute__((ext_vector_type(4)));

static __device__ __forceinline__ unsigned short f2bu(float f) {
    bf16 h = __float2bfloat16(f);
    return *reinterpret_cast<unsigned short*>(&h);
}
static __device__ __forceinline__ float bulo(unsigned int u) {   // low bf16 of pair
    return __uint_as_float(u << 16);
}
static __device__ __forceinline__ float buhi(unsigned int u) {   // high bf16 of pair
    return __uint_as_float(u & 0xffff0000u);
}
static __device__ __forceinline__ unsigned int packbf(float lo, float hi) {
    return (unsigned int)f2bu(lo) | ((unsigned int)f2bu(hi) << 16);
}
static __device__ __forceinline__ void gload_lds16(const void* g, void* l) {
    __builtin_amdgcn_global_load_lds(
        (const __attribute__((address_space(1))) unsigned int*)g,
        (__attribute__((address_space(3))) unsigned int*)l, 16, 0, 0);
}

// ---------------- degree / dinv ----------------
__global__ void k_init(int* __restrict__ deg, int* __restrict__ cursor, int n) {
    int i = blockIdx.x * 256 + threadIdx.x;
    if (i < n) { deg[i] = 1; cursor[i] = 0; }  // self-loop counts 1
}

__global__ void k_count(const int* __restrict__ col, int* __restrict__ deg, int e) {
    int i = blockIdx.x * 256 + threadIdx.x;
    if (i < e) atomicAdd(&deg[col[i]], 1);
}

__global__ void k_dinv(const int* __restrict__ deg, float* __restrict__ dinv, int n) {
    int i = blockIdx.x * 256 + threadIdx.x;
    if (i < n) dinv[i] = rsqrtf((float)deg[i]);
}

// ---------------- exclusive scan of (deg[i]-1) = in-degree ----------------
__global__ void k_scanA(const int* __restrict__ deg, int* __restrict__ ex,
                        int* __restrict__ bsum, int n) {
    __shared__ int sh[256];
    int tid = threadIdx.x;
    int base = blockIdx.x * 1024 + tid * 4;
    int v[4]; int s = 0;
#pragma unroll
    for (int t = 0; t < 4; t++) {
        int i = base + t;
        v[t] = (i < n) ? (deg[i] - 1) : 0;
        s += v[t];
    }
    sh[tid] = s;
    __syncthreads();
    for (int off = 1; off < 256; off <<= 1) {
        int t = (tid >= off) ? sh[tid - off] : 0;
        __syncthreads();
        sh[tid] += t;
        __syncthreads();
    }
    int excl = sh[tid] - s;
#pragma unroll
    for (int t = 0; t < 4; t++) {
        int i = base + t;
        if (i < n) ex[i] = excl;
        excl += v[t];
    }
    if (tid == 255) bsum[blockIdx.x] = sh[255];
}

__global__ void k_scanB(const int* __restrict__ bsum, int* __restrict__ bexc, int nb) {
    __shared__ int sh[256];
    int tid = threadIdx.x;
    int s = (tid < nb) ? bsum[tid] : 0;
    sh[tid] = s;
    __syncthreads();
    for (int off = 1; off < 256; off <<= 1) {
        int t = (tid >= off) ? sh[tid - off] : 0;
        __syncthreads();
        sh[tid] += t;
        __syncthreads();
    }
    bexc[tid] = sh[tid] - s;
}

__global__ void k_scanC(int* __restrict__ starts, const int* __restrict__ bexc, int n) {
    int i = blockIdx.x * 256 + threadIdx.x;
    if (i < n) starts[i] += bexc[i >> 10];
}

// ---------------- CSR fill (by destination), packed (src,weight) ----------------
__global__ void k_fill(const int* __restrict__ ei, const float* __restrict__ dinv,
                       const int* __restrict__ starts, int* __restrict__ cursor,
                       uint2* __restrict__ edges, int e) {
    int i = blockIdx.x * 256 + threadIdx.x;
    if (i < e) {
        int r = ei[i];          // source
        int c = ei[e + i];      // destination (aggregation index)
        int p = atomicAdd(&cursor[c], 1);
        edges[starts[c] + p] = make_uint2((unsigned int)r,
                                          __float_as_uint(dinv[r] * dinv[c]));
    }
}

// ---------------- x -> bf16 (packed uints, 16B stores) ----------------
__global__ void k_cvtx(const float* __restrict__ x, unsigned int* __restrict__ xb32,
                       long total8) {
    long g = (long)blockIdx.x * 256 + threadIdx.x;
    if (g < total8) {
        const float4* xp = (const float4*)(x + g * 8);
        float4 v0 = xp[0], v1 = xp[1];
        uint4 o;
        o.x = packbf(v0.x, v0.y); o.y = packbf(v0.z, v0.w);
        o.z = packbf(v1.x, v1.y); o.w = packbf(v1.z, v1.w);
        *(uint4*)(xb32 + g * 4) = o;
    }
}

// ---------------- W -> bf16 B^T layout [JP][KP], zero-padded ----------------
__global__ void k_twb(const float* __restrict__ W, unsigned short* __restrict__ wbp) {
    int idx = blockIdx.x * 256 + threadIdx.x;
    if (idx < JP * KP) {
        int j = idx / KP, k = idx - j * KP;
        wbp[idx] = (j < D && k < D) ? f2bu(W[j * D + k]) : (unsigned short)0;
    }
}

// ---------------- gather (fp32 x fallback): one wave per node ----------------
__global__ void k_gather_f32(const float* __restrict__ x, const uint2* __restrict__ edges,
                             const int* __restrict__ starts, const int* __restrict__ deg,
                             const float* __restrict__ dinv,
                             unsigned short* __restrict__ hbp, int n) {
    int w = (blockIdx.x * blockDim.x + threadIdx.x) >> 6;
    if (w >= n) return;
    int lane = threadIdx.x & 63;
    int s = starts[w];
    int cnt = deg[w] - 1;
    float dc = dinv[w];
    float a0 = 0.f, a1 = 0.f, a2 = 0.f, a3 = 0.f, a4 = 0.f;
    const bool d4 = lane < (D - 256);
    for (int t = 0; t < cnt; t++) {
        uint2 ed = edges[s + t];
        float wg = __uint_as_float(ed.y);
        const float* xr = x + (size_t)ed.x * D + lane;
        a0 += wg * xr[0]; a1 += wg * xr[64]; a2 += wg * xr[128]; a3 += wg * xr[192];
        if (d4) a4 += wg * xr[256];
    }
    const float* xc = x + (size_t)w * D + lane;
    float sw = dc * dc;
    a0 += sw * xc[0]; a1 += sw * xc[64]; a2 += sw * xc[128]; a3 += sw * xc[192];
    if (d4) a4 += sw * xc[256];
    unsigned short* hc = hbp + (size_t)w * KP + lane;
    hc[0]   = f2bu(a0);
    hc[64]  = f2bu(a1);
    hc[128] = f2bu(a2);
    hc[192] = f2bu(a3);
    hc[256] = d4 ? f2bu(a4) : (unsigned short)0;
}

// ---------------- gather (bf16 x, uint2 loads, 4-edge unroll) ----------------
// x row = 75 uint2 (300 bf16). lane covers uint2 slots {lane} + {64+lane if lane<11}.
__global__ void k_gather_bf(const uint2* __restrict__ xb2, const uint2* __restrict__ edges,
                            const int* __restrict__ starts, const int* __restrict__ deg,
                            const float* __restrict__ dinv, uint2* __restrict__ hb2, int n) {
    int w = (blockIdx.x * blockDim.x + threadIdx.x) >> 6;
    if (w >= n) return;
    int lane = threadIdx.x & 63;
    int s = starts[w];
    int cnt = deg[w] - 1;
    float dc = dinv[w];
    const bool p2 = lane < 11;   // 64 + 11 = 75 uint2 per row
    float a0 = 0.f, a1 = 0.f, a2 = 0.f, a3 = 0.f;
    float a4 = 0.f, a5 = 0.f, a6 = 0.f, a7 = 0.f;
    const uint2 Z = make_uint2(0u, 0u);

#define GACC(ua, ub, wgt)                                                     \
    {                                                                         \
        a0 += (wgt) * bulo((ua).x); a1 += (wgt) * buhi((ua).x);               \
        a2 += (wgt) * bulo((ua).y); a3 += (wgt) * buhi((ua).y);               \
        a4 += (wgt) * bulo((ub).x); a5 += (wgt) * buhi((ub).x);               \
        a6 += (wgt) * bulo((ub).y); a7 += (wgt) * buhi((ub).y);               \
    }

    int t = 0;
    for (; t + 4 <= cnt; t += 4) {
        uint2 e0 = edges[s + t],     e1 = edges[s + t + 1];
        uint2 e2 = edges[s + t + 2], e3 = edges[s + t + 3];
        const uint2* q0 = xb2 + (size_t)e0.x * 75 + lane;
        const uint2* q1 = xb2 + (size_t)e1.x * 75 + lane;
        const uint2* q2 = xb2 + (size_t)e2.x * 75 + lane;
        const uint2* q3 = xb2 + (size_t)e3.x * 75 + lane;
        uint2 u0a = q0[0], u1a = q1[0], u2a = q2[0], u3a = q3[0];
        uint2 u0b = p2 ? q0[64] : Z;
        uint2 u1b = p2 ? q1[64] : Z;
        uint2 u2b = p2 ? q2[64] : Z;
        uint2 u3b = p2 ? q3[64] : Z;
        float w0 = __uint_as_float(e0.y), w1 = __uint_as_float(e1.y);
        float w2 = __uint_as_float(e2.y), w3 = __uint_as_float(e3.y);
        GACC(u0a, u0b, w0);
        GACC(u1a, u1b, w1);
        GACC(u2a, u2b, w2);
        GACC(u3a, u3b, w3);
    }
    for (; t < cnt; t++) {
        uint2 ed = edges[s + t];
        float wg = __uint_as_float(ed.y);
        const uint2* q = xb2 + (size_t)ed.x * 75 + lane;
        uint2 ua = q[0];
        uint2 ub = p2 ? q[64] : Z;
        GACC(ua, ub, wg);
    }
    {
        float sw = dc * dc;   // self loop
        const uint2* q = xb2 + (size_t)w * 75 + lane;
        uint2 ua = q[0];
        uint2 ub = p2 ? q[64] : Z;
        GACC(ua, ub, sw);
    }
#undef GACC

    uint2* hr = hb2 + (size_t)w * 80;   // 80 uint2 = 320 bf16 per padded row
    hr[lane] = make_uint2(packbf(a0, a1), packbf(a2, a3));
    if (lane < 16)
        hr[64 + lane] = p2 ? make_uint2(packbf(a4, a5), packbf(a6, a7)) : Z;
}

// ------ MFMA GEMM: LDS-staged B (kg-major), 2 row-tiles/wave, fused epilogue ------
// block = 4 waves = 128 rows; wave = 32 rows x 304 cols.
__global__ __launch_bounds__(256)
void k_mm(const unsigned short* __restrict__ hbp, const unsigned short* __restrict__ wbp,
          const float* __restrict__ bias, float* __restrict__ out, int n) {
    __shared__ unsigned short Bsh[2][JP * 32];   // 2 x 19456 B
    int tid = threadIdx.x;
    int lane = tid & 63, wid = tid >> 6;
    int r0 = blockIdx.x * 128 + wid * 32;
    int lrow = lane & 15, kg = lane >> 4;

    int goff[5];
#pragma unroll
    for (int j = 0; j < 5; j++) {
        int i = wid + 4 * j;
        if (i < 19) {
            int u = i * 64 + lane;
            int kgs = u / 304;
            int rs  = u - kgs * 304;
            goff[j] = rs * (KP * 2) + kgs * 16;
        }
    }
    const char* wb = (const char*)wbp;

    int ar0 = r0 + lrow;      if (ar0 >= n) ar0 = n - 1;
    int ar1 = r0 + 16 + lrow; if (ar1 >= n) ar1 = n - 1;
    const us8* ap0 = (const us8*)(hbp + (size_t)ar0 * KP);
    const us8* ap1 = (const us8*)(hbp + (size_t)ar1 * KP);

    f32x4 acc0[NT], acc1[NT];
#pragma unroll
    for (int t = 0; t < NT; t++) {
        acc0[t] = f32x4{0.f, 0.f, 0.f, 0.f};
        acc1[t] = f32x4{0.f, 0.f, 0.f, 0.f};
    }

    {
        char* lb = (char*)&Bsh[0][0];
#pragma unroll
        for (int j = 0; j < 5; j++) {
            int i = wid + 4 * j;
            if (i < 19) gload_lds16(wb + goff[j], lb + i * 1024);
        }
    }
    us8 a0 = ap0[kg], a1 = ap1[kg];
    __syncthreads();

    for (int kk = 0; kk < KP / 32; kk++) {
        if (kk < KP / 32 - 1) {
            char* lb = (char*)&Bsh[(kk + 1) & 1][0];
            int gofs = (kk + 1) * 64;
#pragma unroll
            for (int j = 0; j < 5; j++) {
                int i = wid + 4 * j;
                if (i < 19) gload_lds16(wb + goff[j] + gofs, lb + i * 1024);
            }
        }
        us8 a0n = a0, a1n = a1;
        if (kk < KP / 32 - 1) {
            a0n = ap0[(kk + 1) * 4 + kg];
            a1n = ap1[(kk + 1) * 4 + kg];
        }
        const unsigned short* bbase = &Bsh[kk & 1][0] + (kg * 304 + lrow) * 8;
        bf16x8 av0 = __builtin_bit_cast(bf16x8, a0);
        bf16x8 av1 = __builtin_bit_cast(bf16x8, a1);
#pragma unroll
        for (int t = 0; t < NT; t++) {
            bf16x8 bv = __builtin_bit_cast(bf16x8, *(const us8*)(bbase + t * 128));
            acc0[t] = __builtin_amdgcn_mfma_f32_16x16x32_bf16(av0, bv, acc0[t], 0, 0, 0);
            acc1[t] = __builtin_amdgcn_mfma_f32_16x16x32_bf16(av1, bv, acc1[t], 0, 0, 0);
        }
        a0 = a0n; a1 = a1n;
        __syncthreads();
    }

    float bj[NT];
#pragma unroll
    for (int t = 0; t < NT; t++) {
        int j = t * 16 + lrow;
        bj[t] = (j < D) ? bias[j] : 0.f;
    }
    float s0[4] = {0.f, 0.f, 0.f, 0.f}, s1[4] = {0.f, 0.f, 0.f, 0.f};
#pragma unroll
    for (int t = 0; t < NT; t++) {
#pragma unroll
        for (int r = 0; r < 4; r++) {
            float v = acc0[t][r] + bj[t];
            v = v > 0.f ? v : 0.f;
            acc0[t][r] = v; s0[r] += v * v;
            float u = acc1[t][r] + bj[t];
            u = u > 0.f ? u : 0.f;
            acc1[t][r] = u; s1[r] += u * u;
        }
    }
#pragma unroll
    for (int r = 0; r < 4; r++) {
        float a = s0[r], b = s1[r];
        a += __shfl_xor(a, 1); b += __shfl_xor(b, 1);
        a += __shfl_xor(a, 2); b += __shfl_xor(b, 2);
        a += __shfl_xor(a, 4); b += __shfl_xor(b, 4);
        a += __shfl_xor(a, 8); b += __shfl_xor(b, 8);
        s0[r] = rsqrtf(fmaxf(a, 1e-24f));   // == 1/max(sqrt(a),1e-12)
        s1[r] = rsqrtf(fmaxf(b, 1e-24f));
    }
#pragma unroll
    for (int r = 0; r < 4; r++) {
        int g0 = r0 + kg * 4 + r;          // C/D: row=(lane>>4)*4+reg
        int g1 = r0 + 16 + kg * 4 + r;
        float* op0 = out + (size_t)g0 * D;
        float* op1 = out + (size_t)g1 * D;
#pragma unroll
        for (int t = 0; t < NT; t++) {
            int j = t * 16 + lrow;
            if (j < D) {
                if (g0 < n) op0[j] = acc0[t][r] * s0[r];
                if (g1 < n) op1[j] = acc1[t][r] * s1[r];
            }
        }
    }
}

// ---------------- host launch ----------------
extern "C" void kernel_launch(void* const* d_in, const int* in_sizes, int n_in,
                              void* d_out, int out_size, void* d_ws, size_t ws_size,
                              hipStream_t stream) {
    const float* x  = (const float*)d_in[0];
    const int*   ei = (const int*)d_in[1];
    const float* W  = (const float*)d_in[2];
    const float* b  = (const float*)d_in[3];
    float* out = (float*)d_out;
    int n = in_sizes[0] / D;
    int e = in_sizes[1] / 2;

    char* p = (char*)d_ws;
    unsigned short* hbp = (unsigned short*)p; p += (size_t)n * KP * 2;
    int* deg = (int*)p;         p += (size_t)n * 4;
    float* dinv = (float*)p;    p += (size_t)n * 4;
    int* starts = (int*)p;      p += (size_t)n * 4;
    int* cursor = (int*)p;      p += (size_t)n * 4;
    p = (char*)(((uintptr_t)p + 15) & ~(uintptr_t)15);
    uint2* edges = (uint2*)p;   p += (size_t)e * 8;
    int* bsum = (int*)p;        p += 256 * 4;
    int* bexc = (int*)p;        p += 256 * 4;
    p = (char*)(((uintptr_t)p + 15) & ~(uintptr_t)15);
    unsigned short* wbp = (unsigned short*)p; p += (size_t)JP * KP * 2;
    p = (char*)(((uintptr_t)p + 15) & ~(uintptr_t)15);
    unsigned int* xb32 = (unsigned int*)p;
    size_t need_bf = (size_t)(p - (char*)d_ws) + (size_t)n * D * 2;
    bool usebf = (ws_size >= need_bf) && (((long)n * D) % 8 == 0);

    int nb = (n + 1023) / 1024;

    k_init <<<(n + 255) / 256, 256, 0, stream>>>(deg, cursor, n);
    k_count<<<(e + 255) / 256, 256, 0, stream>>>(ei + e, deg, e);
    k_dinv <<<(n + 255) / 256, 256, 0, stream>>>(deg, dinv, n);
    k_scanA<<<nb, 256, 0, stream>>>(deg, starts, bsum, n);
    k_scanB<<<1, 256, 0, stream>>>(bsum, bexc, nb);
    k_scanC<<<(n + 255) / 256, 256, 0, stream>>>(starts, bexc, n);
    k_fill <<<(e + 255) / 256, 256, 0, stream>>>(ei, dinv, starts, cursor, edges, e);
    k_twb  <<<(JP * KP + 255) / 256, 256, 0, stream>>>(W, wbp);
    if (usebf) {
        long g8 = ((long)n * D) / 8;
        k_cvtx<<<(int)((g8 + 255) / 256), 256, 0, stream>>>(x, xb32, g8);
        k_gather_bf<<<(n + 3) / 4, 256, 0, stream>>>((const uint2*)xb32, edges, starts,
                                                     deg, dinv, (uint2*)hbp, n);
    } else {
        k_gather_f32<<<(n + 3) / 4, 256, 0, stream>>>(x, edges, starts, deg, dinv, hbp, n);
    }
    k_mm <<<(n + 127) / 128, 256, 0, stream>>>(hbp, wbp, b, out, n);
}

// Round 6
// 291.125 us; speedup vs baseline: 2.6938x; 1.0263x over previous
//
#include <hip/hip_runtime.h>
#include <hip/hip_bf16.h>
#include <stdint.h>

#define D 300
#define KP 320   // K padded to 10*32 (W side; A side masked)
#define JP 304   // out-col padded to 19*16
#define NT 19    // col tiles (16 wide) per wave

typedef __hip_bfloat16 bf16;
typedef __bf16 bf16x8 __attribute__((ext_vector_type(8)));
typedef unsigned short us8 __attribute__((ext_vector_type(8)));
typedef float f32x4 __attribute__((ext_vector_type(4)));

static __device__ __forceinline__ unsigned short f2bu(float f) {
    bf16 h = __float2bfloat16(f);
    return *reinterpret_cast<unsigned short*>(&h);
}
static __device__ __forceinline__ float bulo(unsigned int u) {
    return __uint_as_float(u << 16);
}
static __device__ __forceinline__ float buhi(unsigned int u) {
    return __uint_as_float(u & 0xffff0000u);
}
static __device__ __forceinline__ void gload_lds16(const void* g, void* l) {
    __builtin_amdgcn_global_load_lds(
        (const __attribute__((address_space(1))) unsigned int*)g,
        (__attribute__((address_space(3))) unsigned int*)l, 16, 0, 0);
}
// 8 floats of row at [o, o+8) -> bf16x8 bits, zero-masked beyond D
static __device__ __forceinline__ us8 loadA8(const float* __restrict__ row, int o) {
    float4 va = {0.f, 0.f, 0.f, 0.f}, vb = {0.f, 0.f, 0.f, 0.f};
    if (o + 4 <= D) va = *(const float4*)(row + o);
    if (o + 8 <= D) vb = *(const float4*)(row + o + 4);
    us8 u;
    u[0] = f2bu(va.x); u[1] = f2bu(va.y); u[2] = f2bu(va.z); u[3] = f2bu(va.w);
    u[4] = f2bu(vb.x); u[5] = f2bu(vb.y); u[6] = f2bu(vb.z); u[7] = f2bu(vb.w);
    return u;
}

// ---------------- degree / dinv ----------------
__global__ void k_init(int* __restrict__ deg, int* __restrict__ cursor, int n) {
    int i = blockIdx.x * 256 + threadIdx.x;
    if (i < n) { deg[i] = 1; cursor[i] = 0; }  // self-loop counts 1
}

__global__ void k_count(const int* __restrict__ col, int* __restrict__ deg, int e) {
    int i = blockIdx.x * 256 + threadIdx.x;
    if (i < e) atomicAdd(&deg[col[i]], 1);
}

__global__ void k_dinv(const int* __restrict__ deg, float* __restrict__ dinv, int n) {
    int i = blockIdx.x * 256 + threadIdx.x;
    if (i < n) dinv[i] = rsqrtf((float)deg[i]);
}

// ---------------- exclusive scan of (deg[i]-1) = in-degree ----------------
__global__ void k_scanA(const int* __restrict__ deg, int* __restrict__ ex,
                        int* __restrict__ bsum, int n) {
    __shared__ int sh[256];
    int tid = threadIdx.x;
    int base = blockIdx.x * 1024 + tid * 4;
    int v[4]; int s = 0;
#pragma unroll
    for (int t = 0; t < 4; t++) {
        int i = base + t;
        v[t] = (i < n) ? (deg[i] - 1) : 0;
        s += v[t];
    }
    sh[tid] = s;
    __syncthreads();
    for (int off = 1; off < 256; off <<= 1) {
        int t = (tid >= off) ? sh[tid - off] : 0;
        __syncthreads();
        sh[tid] += t;
        __syncthreads();
    }
    int excl = sh[tid] - s;
#pragma unroll
    for (int t = 0; t < 4; t++) {
        int i = base + t;
        if (i < n) ex[i] = excl;
        excl += v[t];
    }
    if (tid == 255) bsum[blockIdx.x] = sh[255];
}

__global__ void k_scanB(const int* __restrict__ bsum, int* __restrict__ bexc, int nb) {
    __shared__ int sh[256];
    int tid = threadIdx.x;
    int s = (tid < nb) ? bsum[tid] : 0;
    sh[tid] = s;
    __syncthreads();
    for (int off = 1; off < 256; off <<= 1) {
        int t = (tid >= off) ? sh[tid - off] : 0;
        __syncthreads();
        sh[tid] += t;
        __syncthreads();
    }
    bexc[tid] = sh[tid] - s;
}

__global__ void k_scanC(int* __restrict__ starts, const int* __restrict__ bexc, int n) {
    int i = blockIdx.x * 256 + threadIdx.x;
    if (i < n) starts[i] += bexc[i >> 10];
}

// ---------------- CSR fill (by destination), packed (src,weight) ----------------
__global__ void k_fill(const int* __restrict__ ei, const float* __restrict__ dinv,
                       const int* __restrict__ starts, int* __restrict__ cursor,
                       uint2* __restrict__ edges, int e) {
    int i = blockIdx.x * 256 + threadIdx.x;
    if (i < e) {
        int r = ei[i];          // source
        int c = ei[e + i];      // destination (aggregation index)
        int p = atomicAdd(&cursor[c], 1);
        edges[starts[c] + p] = make_uint2((unsigned int)r,
                                          __float_as_uint(dinv[r] * dinv[c]));
    }
}

// ---------------- W -> bf16 B^T layout [JP][KP], zero-padded ----------------
__global__ void k_twb(const float* __restrict__ W, unsigned short* __restrict__ wbp) {
    int idx = blockIdx.x * 256 + threadIdx.x;
    if (idx < JP * KP) {
        int j = idx / KP, k = idx - j * KP;
        wbp[idx] = (j < D && k < D) ? f2bu(W[j * D + k]) : (unsigned short)0;
    }
}

// ------ z = x @ W^T in bf16: MFMA, LDS-staged W (kg-major), 2 row-tiles/wave ------
// block = 4 waves = 128 rows; wave = 32 rows x 304 cols. zb row stride = JP bf16.
__global__ __launch_bounds__(256)
void k_zmm(const float* __restrict__ x, const unsigned short* __restrict__ wbp,
           unsigned short* __restrict__ zb, int n) {
    __shared__ unsigned short Bsh[2][JP * 32];   // 2 x 19456 B
    int tid = threadIdx.x;
    int lane = tid & 63, wid = tid >> 6;
    int r0 = blockIdx.x * 128 + wid * 32;
    int lrow = lane & 15, kg = lane >> 4;

    int goff[5];
#pragma unroll
    for (int j = 0; j < 5; j++) {
        int i = wid + 4 * j;
        if (i < 19) {
            int u = i * 64 + lane;
            int kgs = u / 304;
            int rs  = u - kgs * 304;
            goff[j] = rs * (KP * 2) + kgs * 16;
        }
    }
    const char* wb = (const char*)wbp;

    int ar0 = r0 + lrow;      if (ar0 >= n) ar0 = n - 1;
    int ar1 = r0 + 16 + lrow; if (ar1 >= n) ar1 = n - 1;
    const float* xr0 = x + (size_t)ar0 * D;
    const float* xr1 = x + (size_t)ar1 * D;

    f32x4 acc0[NT], acc1[NT];
#pragma unroll
    for (int t = 0; t < NT; t++) {
        acc0[t] = f32x4{0.f, 0.f, 0.f, 0.f};
        acc1[t] = f32x4{0.f, 0.f, 0.f, 0.f};
    }

    {
        char* lb = (char*)&Bsh[0][0];
#pragma unroll
        for (int j = 0; j < 5; j++) {
            int i = wid + 4 * j;
            if (i < 19) gload_lds16(wb + goff[j], lb + i * 1024);
        }
    }
    us8 a0 = loadA8(xr0, kg * 8);
    us8 a1 = loadA8(xr1, kg * 8);
    __syncthreads();

    for (int kk = 0; kk < KP / 32; kk++) {
        if (kk < KP / 32 - 1) {
            char* lb = (char*)&Bsh[(kk + 1) & 1][0];
            int gofs = (kk + 1) * 64;
#pragma unroll
            for (int j = 0; j < 5; j++) {
                int i = wid + 4 * j;
                if (i < 19) gload_lds16(wb + goff[j] + gofs, lb + i * 1024);
            }
        }
        us8 a0n = a0, a1n = a1;
        if (kk < KP / 32 - 1) {
            int o = (kk + 1) * 32 + kg * 8;
            a0n = loadA8(xr0, o);
            a1n = loadA8(xr1, o);
        }
        const unsigned short* bbase = &Bsh[kk & 1][0] + (kg * 304 + lrow) * 8;
        bf16x8 av0 = __builtin_bit_cast(bf16x8, a0);
        bf16x8 av1 = __builtin_bit_cast(bf16x8, a1);
#pragma unroll
        for (int t = 0; t < NT; t++) {
            bf16x8 bv = __builtin_bit_cast(bf16x8, *(const us8*)(bbase + t * 128));
            acc0[t] = __builtin_amdgcn_mfma_f32_16x16x32_bf16(av0, bv, acc0[t], 0, 0, 0);
            acc1[t] = __builtin_amdgcn_mfma_f32_16x16x32_bf16(av1, bv, acc1[t], 0, 0, 0);
        }
        a0 = a0n; a1 = a1n;
        __syncthreads();
    }

    // store z rows (bf16, includes zero pad cols 300..303)
#pragma unroll
    for (int r = 0; r < 4; r++) {
        int g0 = r0 + kg * 4 + r;          // C/D: row=(lane>>4)*4+reg
        int g1 = r0 + 16 + kg * 4 + r;
        unsigned short* zp0 = zb + (size_t)g0 * JP;
        unsigned short* zp1 = zb + (size_t)g1 * JP;
#pragma unroll
        for (int t = 0; t < NT; t++) {
            int j = t * 16 + lrow;
            if (g0 < n) zp0[j] = f2bu(acc0[t][r]);
            if (g1 < n) zp1[j] = f2bu(acc1[t][r]);
        }
    }
}

// ------ gather on z + fused epilogue: self-loop, bias, relu, L2-norm, fp32 out ------
// z row = 76 uint2 (304 bf16). lane covers uint2 slots {lane} + {64+lane if lane<12}.
// one wave per node.
__global__ void k_zgather(const uint2* __restrict__ zb2, const uint2* __restrict__ edges,
                          const int* __restrict__ starts, const int* __restrict__ deg,
                          const float* __restrict__ dinv, const float* __restrict__ bias,
                          float* __restrict__ out, int n) {
    int w = (blockIdx.x * blockDim.x + threadIdx.x) >> 6;
    if (w >= n) return;
    int lane = threadIdx.x & 63;
    int s = starts[w];
    int cnt = deg[w] - 1;
    float dc = dinv[w];
    const bool p2 = lane < 12;   // slots 64..75
    float a0 = 0.f, a1 = 0.f, a2 = 0.f, a3 = 0.f;
    float a4 = 0.f, a5 = 0.f, a6 = 0.f, a7 = 0.f;
    const uint2 Z = make_uint2(0u, 0u);

#define GACC(ua, ub, wgt)                                                     \
    {                                                                         \
        a0 += (wgt) * bulo((ua).x); a1 += (wgt) * buhi((ua).x);               \
        a2 += (wgt) * bulo((ua).y); a3 += (wgt) * buhi((ua).y);               \
        a4 += (wgt) * bulo((ub).x); a5 += (wgt) * buhi((ub).x);               \
        a6 += (wgt) * bulo((ub).y); a7 += (wgt) * buhi((ub).y);               \
    }

    int t = 0;
    for (; t + 4 <= cnt; t += 4) {
        uint2 e0 = edges[s + t],     e1 = edges[s + t + 1];
        uint2 e2 = edges[s + t + 2], e3 = edges[s + t + 3];
        const uint2* q0 = zb2 + (size_t)e0.x * 76 + lane;
        const uint2* q1 = zb2 + (size_t)e1.x * 76 + lane;
        const uint2* q2 = zb2 + (size_t)e2.x * 76 + lane;
        const uint2* q3 = zb2 + (size_t)e3.x * 76 + lane;
        uint2 u0a = q0[0], u1a = q1[0], u2a = q2[0], u3a = q3[0];
        uint2 u0b = p2 ? q0[64] : Z;
        uint2 u1b = p2 ? q1[64] : Z;
        uint2 u2b = p2 ? q2[64] : Z;
        uint2 u3b = p2 ? q3[64] : Z;
        float w0 = __uint_as_float(e0.y), w1 = __uint_as_float(e1.y);
        float w2 = __uint_as_float(e2.y), w3 = __uint_as_float(e3.y);
        GACC(u0a, u0b, w0);
        GACC(u1a, u1b, w1);
        GACC(u2a, u2b, w2);
        GACC(u3a, u3b, w3);
    }
    for (; t < cnt; t++) {
        uint2 ed = edges[s + t];
        float wg = __uint_as_float(ed.y);
        const uint2* q = zb2 + (size_t)ed.x * 76 + lane;
        uint2 ua = q[0];
        uint2 ub = p2 ? q[64] : Z;
        GACC(ua, ub, wg);
    }
    {
        float sw = dc * dc;   // self loop
        const uint2* q = zb2 + (size_t)w * 76 + lane;
        uint2 ua = q[0];
        uint2 ub = p2 ? q[64] : Z;
        GACC(ua, ub, sw);
    }
#undef GACC

    // bias + relu
    float4 b0 = *(const float4*)(bias + 4 * lane);        // dims 4l..4l+3 (<256)
    float4 b1 = {0.f, 0.f, 0.f, 0.f};
    const bool wr2 = lane < 11;                           // dims 256..299
    if (wr2) b1 = *(const float4*)(bias + 256 + 4 * lane);
    float v0 = fmaxf(a0 + b0.x, 0.f), v1 = fmaxf(a1 + b0.y, 0.f);
    float v2 = fmaxf(a2 + b0.z, 0.f), v3 = fmaxf(a3 + b0.w, 0.f);
    float v4 = fmaxf(a4 + b1.x, 0.f), v5 = fmaxf(a5 + b1.y, 0.f);
    float v6 = fmaxf(a6 + b1.z, 0.f), v7 = fmaxf(a7 + b1.w, 0.f);
    // row sum of squares (pad dims contribute 0)
    float sq = v0 * v0 + v1 * v1 + v2 * v2 + v3 * v3
             + v4 * v4 + v5 * v5 + v6 * v6 + v7 * v7;
    sq += __shfl_xor(sq, 1);
    sq += __shfl_xor(sq, 2);
    sq += __shfl_xor(sq, 4);
    sq += __shfl_xor(sq, 8);
    sq += __shfl_xor(sq, 16);
    sq += __shfl_xor(sq, 32);
    float sc = rsqrtf(fmaxf(sq, 1e-24f));   // == 1/max(sqrt(sq),1e-12)

    float* op = out + (size_t)w * D;
    *(float4*)(op + 4 * lane) = make_float4(v0 * sc, v1 * sc, v2 * sc, v3 * sc);
    if (wr2)
        *(float4*)(op + 256 + 4 * lane) = make_float4(v4 * sc, v5 * sc, v6 * sc, v7 * sc);
}

// ---------------- host launch ----------------
extern "C" void kernel_launch(void* const* d_in, const int* in_sizes, int n_in,
                              void* d_out, int out_size, void* d_ws, size_t ws_size,
                              hipStream_t stream) {
    const float* x  = (const float*)d_in[0];
    const int*   ei = (const int*)d_in[1];
    const float* W  = (const float*)d_in[2];
    const float* b  = (const float*)d_in[3];
    float* out = (float*)d_out;
    int n = in_sizes[0] / D;
    int e = in_sizes[1] / 2;

    char* p = (char*)d_ws;
    unsigned short* zb = (unsigned short*)p; p += (size_t)n * JP * 2;
    int* deg = (int*)p;         p += (size_t)n * 4;
    float* dinv = (float*)p;    p += (size_t)n * 4;
    int* starts = (int*)p;      p += (size_t)n * 4;
    int* cursor = (int*)p;      p += (size_t)n * 4;
    p = (char*)(((uintptr_t)p + 15) & ~(uintptr_t)15);
    uint2* edges = (uint2*)p;   p += (size_t)e * 8;
    int* bsum = (int*)p;        p += 256 * 4;
    int* bexc = (int*)p;        p += 256 * 4;
    p = (char*)(((uintptr_t)p + 15) & ~(uintptr_t)15);
    unsigned short* wbp = (unsigned short*)p; p += (size_t)JP * KP * 2;

    int nb = (n + 1023) / 1024;

    k_init <<<(n + 255) / 256, 256, 0, stream>>>(deg, cursor, n);
    k_count<<<(e + 255) / 256, 256, 0, stream>>>(ei + e, deg, e);
    k_dinv <<<(n + 255) / 256, 256, 0, stream>>>(deg, dinv, n);
    k_scanA<<<nb, 256, 0, stream>>>(deg, starts, bsum, n);
    k_scanB<<<1, 256, 0, stream>>>(bsum, bexc, nb);
    k_scanC<<<(n + 255) / 256, 256, 0, stream>>>(starts, bexc, n);
    k_fill <<<(e + 255) / 256, 256, 0, stream>>>(ei, dinv, starts, cursor, edges, e);
    k_twb  <<<(JP * KP + 255) / 256, 256, 0, stream>>>(W, wbp);
    k_zmm  <<<(n + 127) / 128, 256, 0, stream>>>(x, wbp, zb, n);
    k_zgather<<<(n + 3) / 4, 256, 0, stream>>>((const uint2*)zb, edges, starts, deg,
                                               dinv, b, out, n);
}